// Round 8
// baseline (232.663 us; speedup 1.0000x reference)
//
#include <hip/hip_runtime.h>
#include <hip/hip_bf16.h>
#include <math.h>

// Problem constants (B, S, E, D) for SA_Layer_45603962749650
#define Bb 8
#define Ss 2048
#define Ee 512
#define Dd 512
#define QSPLIT 16   // one partial per 128-row scores tile

typedef __bf16 bf16x8 __attribute__((ext_vector_type(8)));
typedef __bf16 bf16x4 __attribute__((ext_vector_type(4)));
typedef float f32x4 __attribute__((ext_vector_type(4)));

// ---------------------------------------------------------------------------
// Async-stage one 128x32 bf16 tile into swizzled LDS [128][32], 4-wave blocks.
// Chunk c (16B) of row r lives at physical chunk c ^ ((r>>1)&3).
// ---------------------------------------------------------------------------
__device__ __forceinline__ void stage_async(ushort* lds, const __bf16* gbase,
                                            int ldg, int wave, int lane) {
#pragma unroll
    for (int t = 0; t < 2; ++t) {
        const int idx = wave * 2 + t;               // 16-row chunk 0..7
        const int row = idx * 16 + (lane >> 2);
        const int q8  = (((lane & 3) ^ ((lane >> 3) & 3)) * 8);
        __builtin_amdgcn_global_load_lds(
            (const __attribute__((address_space(1))) void*)(gbase + (size_t)row * ldg + q8),
            (__attribute__((address_space(3))) void*)(lds + idx * 512),
            16, 0, 0);
    }
}

// Same, for 2-wave (128-thread) blocks: each wave stages 4 of 8 chunks.
__device__ __forceinline__ void stage_async2(ushort* lds, const __bf16* gbase,
                                             int ldg, int wave, int lane) {
#pragma unroll
    for (int t = 0; t < 4; ++t) {
        const int idx = wave * 4 + t;
        const int row = idx * 16 + (lane >> 2);
        const int q8  = (((lane & 3) ^ ((lane >> 3) & 3)) * 8);
        __builtin_amdgcn_global_load_lds(
            (const __attribute__((address_space(1))) void*)(gbase + (size_t)row * ldg + q8),
            (__attribute__((address_space(3))) void*)(lds + idx * 512),
            16, 0, 0);
    }
}

// ---------------------------------------------------------------------------
// prep_x: one pass over x. Writes xb = bf16(x) [B,S,E] and xT = bf16(x^T) [B,E,S]
// ---------------------------------------------------------------------------
__global__ void prep_x(const float* __restrict__ in, __bf16* __restrict__ xb,
                       __bf16* __restrict__ xT) {
    __shared__ float tile[32][33];
    const int b  = blockIdx.z;
    const int e0 = blockIdx.x * 32;
    const int s0 = blockIdx.y * 32;
    const float* ip = in + (size_t)b * Ss * Ee;
    __bf16* xbp = xb + (size_t)b * Ss * Ee;
    __bf16* xTp = xT + (size_t)b * Ee * Ss;
    for (int i = threadIdx.y; i < 32; i += 8) {
        const float v = ip[(size_t)(s0 + i) * Ee + e0 + threadIdx.x];
        tile[i][threadIdx.x] = v;
        xbp[(size_t)(s0 + i) * Ee + e0 + threadIdx.x] = (__bf16)v;
    }
    __syncthreads();
    for (int i = threadIdx.y; i < 32; i += 8)
        xTp[(size_t)(e0 + i) * Ss + s0 + threadIdx.x] = (__bf16)tile[threadIdx.x][i];
}

// ---------------------------------------------------------------------------
// Transpose 512x512: f32 in -> bf16 out. blockIdx.z selects Wq/Wk.
// ---------------------------------------------------------------------------
__global__ void transpose_w(const float* __restrict__ Wq, const float* __restrict__ Wk,
                            __bf16* __restrict__ WqT, __bf16* __restrict__ WkT) {
    __shared__ float tile[32][33];
    const float* in = blockIdx.z ? Wk : Wq;
    __bf16* out = blockIdx.z ? WkT : WqT;
    const int x0 = blockIdx.x * 32;
    const int y0 = blockIdx.y * 32;
    for (int i = threadIdx.y; i < 32; i += 8)
        tile[i][threadIdx.x] = in[(size_t)(y0 + i) * 512 + (x0 + threadIdx.x)];
    __syncthreads();
    for (int i = threadIdx.y; i < 32; i += 8)
        out[(size_t)(x0 + i) * 512 + (y0 + threadIdx.x)] = (__bf16)tile[threadIdx.x][i];
}

// ---------------------------------------------------------------------------
// Projection GEMM (NT): Out = relu(X @ W + b), 128x128 tile, BK=32, async+swizzle.
// ---------------------------------------------------------------------------
__global__ __launch_bounds__(256, 4) void proj_kernel(
    const __bf16* __restrict__ X,
    const __bf16* __restrict__ WqT, const __bf16* __restrict__ WkT,
    const float* __restrict__ bq, const float* __restrict__ bk,
    __bf16* __restrict__ qb, __bf16* __restrict__ kb)
{
    __shared__ __align__(16) ushort As[128 * 32];
    __shared__ __align__(16) ushort Bs[128 * 32];
    const __bf16* WT  = blockIdx.z ? WkT : WqT;
    const float* bias = blockIdx.z ? bk : bq;
    __bf16* Out       = blockIdx.z ? kb : qb;

    const int tid = threadIdx.x;
    const int wave = tid >> 6, lane = tid & 63, quad = lane >> 4, l16 = lane & 15;
    const int wm = (wave >> 1) * 64, wn = (wave & 1) * 64;
    const int m0 = blockIdx.y * 128, n0 = blockIdx.x * 128;
    const int sw = (quad ^ ((l16 >> 1) & 3)) * 8;
    const int K = 512;

    f32x4 acc[4][4];
    f32x4 zero = {0.f, 0.f, 0.f, 0.f};
    for (int i = 0; i < 4; i++) for (int j = 0; j < 4; j++) acc[i][j] = zero;

    for (int k0 = 0; k0 < K; k0 += 32) {
        stage_async(As, X  + (size_t)m0 * K + k0, K, wave, lane);
        stage_async(Bs, WT + (size_t)n0 * K + k0, K, wave, lane);
        __syncthreads();
        bf16x8 af[4], bfr[4];
        for (int i = 0; i < 4; i++) af[i]  = *(bf16x8*)&As[(wm + i * 16 + l16) * 32 + sw];
        for (int j = 0; j < 4; j++) bfr[j] = *(bf16x8*)&Bs[(wn + j * 16 + l16) * 32 + sw];
        for (int i = 0; i < 4; i++)
            for (int j = 0; j < 4; j++)
                acc[i][j] = __builtin_amdgcn_mfma_f32_16x16x32_bf16(af[i], bfr[j], acc[i][j], 0, 0, 0);
        __syncthreads();
    }

    for (int i = 0; i < 4; i++) {
        const int row = m0 + wm + i * 16 + quad * 4;
        for (int j = 0; j < 4; j++) {
            const int col = n0 + wn + j * 16 + l16;
            const float bv = bias[col];
            for (int rr = 0; rr < 4; rr++) {
                float v = acc[i][j][rr] + bv;
                v = v > 0.f ? v : 0.f;
                Out[(size_t)(row + rr) * 512 + col] = (__bf16)v;
            }
        }
    }
}

// ---------------------------------------------------------------------------
// Scores GEMM (NT) + fused column-softmax tile stats + bf16 P output.
// 1-D grid, XCD=batch swizzle: b = id&7 keeps qb/kb batch strips L2-resident.
// ---------------------------------------------------------------------------
__global__ __launch_bounds__(256, 4) void scores_kernel(
    const __bf16* __restrict__ Q,   // [B*S, D] bf16
    const __bf16* __restrict__ Km,  // [B*S, D] bf16
    __bf16* __restrict__ P,         // [B, S, S] bf16
    float* __restrict__ Mp,         // [QSPLIT, B, S]
    float* __restrict__ Lp)         // [QSPLIT, B, S]
{
    __shared__ __align__(16) ushort As[128 * 32];
    __shared__ __align__(16) ushort Bs[128 * 32];
    const int id = blockIdx.x;            // 0..2047
    const int b = id & 7;
    const int rest = id >> 3;             // 0..255
    const int qy = rest >> 4;             // q tile 0..15
    const int m0 = qy * 128;
    const int n0 = (rest & 15) * 128;     // k tile
    const __bf16* A  = Q  + (size_t)b * Ss * Dd;
    const __bf16* Bp = Km + (size_t)b * Ss * Dd;
    __bf16* C = P + (size_t)b * Ss * Ss;

    const int tid = threadIdx.x;
    const int wave = tid >> 6, lane = tid & 63, quad = lane >> 4, l16 = lane & 15;
    const int wm = (wave >> 1) * 64, wn = (wave & 1) * 64;
    const int sw = (quad ^ ((l16 >> 1) & 3)) * 8;
    const float scale = 0.044194173824159216f; // 1/sqrt(512)

    f32x4 acc[4][4];
    f32x4 zero = {0.f, 0.f, 0.f, 0.f};
    for (int i = 0; i < 4; i++) for (int j = 0; j < 4; j++) acc[i][j] = zero;

    for (int k0 = 0; k0 < Dd; k0 += 32) {
        stage_async(As, A  + (size_t)m0 * Dd + k0, Dd, wave, lane);
        stage_async(Bs, Bp + (size_t)n0 * Dd + k0, Dd, wave, lane);
        __syncthreads();
        bf16x8 af[4], bfr[4];
        for (int i = 0; i < 4; i++) af[i]  = *(bf16x8*)&As[(wm + i * 16 + l16) * 32 + sw];
        for (int j = 0; j < 4; j++) bfr[j] = *(bf16x8*)&Bs[(wn + j * 16 + l16) * 32 + sw];
        for (int i = 0; i < 4; i++)
            for (int j = 0; j < 4; j++)
                acc[i][j] = __builtin_amdgcn_mfma_f32_16x16x32_bf16(af[i], bfr[j], acc[i][j], 0, 0, 0);
        __syncthreads();
    }

    // ---- tile column max (unscaled; scale>0 commutes with max) ----
    float* Ms = (float*)As;
    float* Ls = ((float*)As) + 256;
    const int half = wave >> 1;
    float mj[4];
    for (int j = 0; j < 4; j++) {
        float m = -1e30f;
        for (int i = 0; i < 4; i++)
            for (int rr = 0; rr < 4; rr++)
                m = fmaxf(m, acc[i][j][rr]);
        m = fmaxf(m, __shfl_xor(m, 16));
        m = fmaxf(m, __shfl_xor(m, 32));
        mj[j] = m;
    }
    if (quad == 0)
        for (int j = 0; j < 4; j++) Ms[half * 128 + wn + j * 16 + l16] = mj[j];
    __syncthreads();
    float mt[4];
    for (int j = 0; j < 4; j++) {
        const int c = wn + j * 16 + l16;
        mt[j] = fmaxf(Ms[c], Ms[128 + c]);
    }
    // ---- exp + P store (bf16) + column sum ----
    float lj[4];
    for (int j = 0; j < 4; j++) {
        const int col = n0 + wn + j * 16 + l16;
        float l = 0.f;
        for (int i = 0; i < 4; i++) {
            const int row = m0 + wm + i * 16 + quad * 4;
            for (int rr = 0; rr < 4; rr++) {
                const float e = __expf((acc[i][j][rr] - mt[j]) * scale);
                C[(size_t)(row + rr) * Ss + col] = (__bf16)e;
                l += e;
            }
        }
        l += __shfl_xor(l, 16);
        l += __shfl_xor(l, 32);
        lj[j] = l;
    }
    if (quad == 0)
        for (int j = 0; j < 4; j++) Ls[half * 128 + wn + j * 16 + l16] = lj[j];
    __syncthreads();
    if (tid < 128) {
        const size_t o = ((size_t)qy * Bb + b) * Ss + n0 + tid;
        Mp[o] = fmaxf(Ms[tid], Ms[128 + tid]) * scale;
        Lp[o] = Ls[tid] + Ls[128 + tid];
    }
}

// ---------------------------------------------------------------------------
// Combine QSPLIT tile partials -> per-tile correction table
// Corr[qy][b][k] = exp(Mp[qy][b][k] - m_global) / sumexp_global
// ---------------------------------------------------------------------------
__global__ void stats_combine(const float* __restrict__ Mp, const float* __restrict__ Lp,
                              float* __restrict__ Corr) {
    const int idx = blockIdx.x * 256 + threadIdx.x;  // over B*S columns
    float m = -1e30f;
    for (int qy = 0; qy < QSPLIT; qy++) m = fmaxf(m, Mp[(size_t)qy * Bb * Ss + idx]);
    float l = 0.f;
    for (int qy = 0; qy < QSPLIT; qy++)
        l += Lp[(size_t)qy * Bb * Ss + idx] * __expf(Mp[(size_t)qy * Bb * Ss + idx] - m);
    const float li = 1.0f / l;
    for (int qy = 0; qy < QSPLIT; qy++)
        Corr[(size_t)qy * Bb * Ss + idx] = __expf(Mp[(size_t)qy * Bb * Ss + idx] - m) * li;
}

// ---------------------------------------------------------------------------
// PV GEMM (NT), 64x128 block tile, 128 threads = 2 waves, wave tile 64x64
// (4x4 of 16x16x32 -> 8 frag reads / 16 MFMA, 1.5x less LDS/FLOP than R7).
// 1024 blocks -> 4 blocks/CU, 8 waves/CU. attn = P * Corr[qy][k] (global,
// L2-resident, prefetched). XCD=batch swizzle (b = id&7). Residual fused.
// ---------------------------------------------------------------------------
__global__ __launch_bounds__(128, 2) void pv_kernel(
    const __bf16* __restrict__ P,    // [B,S,S] bf16 tile-shifted exp scores
    const float* __restrict__ Corr,  // [QSPLIT,B,S]
    const __bf16* __restrict__ XT,   // [B,E,S] bf16
    const __bf16* __restrict__ XB,   // [B,S,E] bf16 (residual)
    float* __restrict__ Out)         // [B,S,E] f32
{
    __shared__ __align__(16) ushort As[64 * 32];    // 4 KB
    __shared__ __align__(16) ushort Bs[128 * 32];   // 8 KB
    const int id = blockIdx.x;            // 0..1023
    const int b = id & 7;
    const int rest = id >> 3;             // 0..127
    const int m0 = (rest >> 2) * 64;      // m tile 0..31 (64 rows)
    const int n0 = (rest & 3) * 128;      // e tile
    const int qy = m0 >> 7;               // 128-row scores-tile index
    const __bf16* A  = P  + (size_t)b * Ss * Ss;
    const __bf16* Bp = XT + (size_t)b * Ee * Ss;
    const float* Cr  = Corr + ((size_t)qy * Bb + b) * Ss;

    const int tid = threadIdx.x;
    const int wave = tid >> 6, lane = tid & 63, quad = lane >> 4, l16 = lane & 15;
    const int wn = wave * 64;
    const int sw = (quad ^ ((l16 >> 1) & 3)) * 8;
    const int r = tid >> 2, seg = (tid & 3) * 8;          // A stage: 32 rows x 4 thr, x2
    const int p8 = (((tid & 3) ^ ((r >> 1) & 3)) * 8);

    f32x4 acc[4][4];
    f32x4 zero = {0.f, 0.f, 0.f, 0.f};
    for (int i = 0; i < 4; i++) for (int j = 0; j < 4; j++) acc[i][j] = zero;

    const __bf16* Arow0 = A + (size_t)(m0 + r) * Ss;
    const __bf16* Arow1 = A + (size_t)(m0 + r + 32) * Ss;
    bf16x8 pr0 = *(const bf16x8*)&Arow0[seg];
    bf16x8 pr1 = *(const bf16x8*)&Arow1[seg];
    float4 cra = *(const float4*)&Cr[seg];
    float4 crb = *(const float4*)&Cr[seg + 4];

    for (int k0 = 0; k0 < Ss; k0 += 32) {
        stage_async2(Bs, Bp + (size_t)n0 * Ss + k0, Ss, wave, lane);
        float cv[8];
        cv[0] = cra.x; cv[1] = cra.y; cv[2] = cra.z; cv[3] = cra.w;
        cv[4] = crb.x; cv[5] = crb.y; cv[6] = crb.z; cv[7] = crb.w;
        bf16x8 o0, o1;
        #pragma unroll
        for (int t = 0; t < 8; t++) o0[t] = (__bf16)((float)pr0[t] * cv[t]);
        #pragma unroll
        for (int t = 0; t < 8; t++) o1[t] = (__bf16)((float)pr1[t] * cv[t]);
        *(bf16x8*)&As[r * 32 + p8]        = o0;
        *(bf16x8*)&As[(r + 32) * 32 + p8] = o1;
        __syncthreads();
        bf16x8 af[4], bfr[4];
        for (int i = 0; i < 4; i++) af[i]  = *(bf16x8*)&As[(i * 16 + l16) * 32 + sw];
        for (int j = 0; j < 4; j++) bfr[j] = *(bf16x8*)&Bs[(wn + j * 16 + l16) * 32 + sw];
        // prefetch next K-step's P and Corr (hide under MFMA block)
        const int kn = (k0 + 32) & (Ss - 1);
        pr0 = *(const bf16x8*)&Arow0[kn + seg];
        pr1 = *(const bf16x8*)&Arow1[kn + seg];
        cra = *(const float4*)&Cr[kn + seg];
        crb = *(const float4*)&Cr[kn + seg + 4];
        for (int i = 0; i < 4; i++)
            for (int j = 0; j < 4; j++)
                acc[i][j] = __builtin_amdgcn_mfma_f32_16x16x32_bf16(af[i], bfr[j], acc[i][j], 0, 0, 0);
        __syncthreads();
    }

    for (int i = 0; i < 4; i++) {
        const int row = m0 + i * 16 + quad * 4;
        for (int j = 0; j < 4; j++) {
            const int col = n0 + wn + j * 16 + l16;
            for (int rr = 0; rr < 4; rr++) {
                const size_t idx = ((size_t)b * Ss + row + rr) * Ee + col;
                Out[idx] = (float)XB[idx] + acc[i][j][rr];
            }
        }
    }
}

// ---------------------------------------------------------------------------
extern "C" void kernel_launch(void* const* d_in, const int* in_sizes, int n_in,
                              void* d_out, int out_size, void* d_ws, size_t ws_size,
                              hipStream_t stream) {
    const float* x  = (const float*)d_in[0];
    const float* Wq = (const float*)d_in[1];
    const float* bq = (const float*)d_in[2];
    const float* Wk = (const float*)d_in[3];
    const float* bk = (const float*)d_in[4];
    float* out = (float*)d_out;

    char* ws = (char*)d_ws;
    size_t off = 0;
    auto alloc = [&](size_t bytes) -> void* {
        void* p = ws + off;
        off += (bytes + 255) & ~(size_t)255;
        return p;
    };
    __bf16* P    = (__bf16*)alloc((size_t)Bb * Ss * Ss * 2);      // 64 MiB
    __bf16* xb   = (__bf16*)alloc((size_t)Bb * Ss * Ee * 2);
    __bf16* qb   = (__bf16*)alloc((size_t)Bb * Ss * Dd * 2);
    __bf16* kb   = (__bf16*)alloc((size_t)Bb * Ss * Dd * 2);
    __bf16* xT   = (__bf16*)alloc((size_t)Bb * Ee * Ss * 2);
    __bf16* WqT  = (__bf16*)alloc((size_t)512 * 512 * 2);
    __bf16* WkT  = (__bf16*)alloc((size_t)512 * 512 * 2);
    float*  Mp   = (float*)alloc((size_t)QSPLIT * Bb * Ss * 4);
    float*  Lp   = (float*)alloc((size_t)QSPLIT * Bb * Ss * 4);
    float*  Corr = (float*)alloc((size_t)QSPLIT * Bb * Ss * 4);   // 1 MiB
    if (off > ws_size) return;

    prep_x<<<dim3(16, 64, 8), dim3(32, 8), 0, stream>>>(x, xb, xT);
    transpose_w<<<dim3(16, 16, 2), dim3(32, 8), 0, stream>>>(Wq, Wk, WqT, WkT);

    // q = relu(x Wq + bq), k = relu(x Wk + bk)
    proj_kernel<<<dim3(4, 128, 2), 256, 0, stream>>>(xb, WqT, WkT, bq, bk, qb, kb);

    // P = exp(q k^T / sqrt(E) - m_tile) bf16 + tile stats   (XCD=batch swizzle)
    scores_kernel<<<dim3(2048), 256, 0, stream>>>(qb, kb, P, Mp, Lp);
    stats_combine<<<dim3(Bb * Ss / 256), 256, 0, stream>>>(Mp, Lp, Corr);

    // out = xb + attn @ x   (64x128 tiles, 2-wave blocks, wave tile 64x64)
    pv_kernel<<<dim3(1024), 128, 0, stream>>>(P, Corr, xT, xb, out);
}

// Round 9
// 228.708 us; speedup vs baseline: 1.0173x; 1.0173x over previous
//
#include <hip/hip_runtime.h>
#include <hip/hip_bf16.h>
#include <math.h>

// Problem constants (B, S, E, D) for SA_Layer_45603962749650
#define Bb 8
#define Ss 2048
#define Ee 512
#define Dd 512
#define QSPLIT 16   // one partial per 128-row scores tile

typedef __bf16 bf16x8 __attribute__((ext_vector_type(8)));
typedef __bf16 bf16x4 __attribute__((ext_vector_type(4)));
typedef float f32x4 __attribute__((ext_vector_type(4)));

// ---------------------------------------------------------------------------
// BK=32 async staging (pv): 128x32 tile, chunk c of row r at phys c^((r>>1)&3).
// ---------------------------------------------------------------------------
__device__ __forceinline__ void stage_async2(ushort* lds, const __bf16* gbase,
                                             int ldg, int wave, int lane) {
#pragma unroll
    for (int t = 0; t < 4; ++t) {
        const int idx = wave * 4 + t;
        const int row = idx * 16 + (lane >> 2);
        const int q8  = (((lane & 3) ^ ((lane >> 3) & 3)) * 8);
        __builtin_amdgcn_global_load_lds(
            (const __attribute__((address_space(1))) void*)(gbase + (size_t)row * ldg + q8),
            (__attribute__((address_space(3))) void*)(lds + idx * 512),
            16, 0, 0);
    }
}

// ---------------------------------------------------------------------------
// BK=64 async staging (scores/proj): 128x64 tile (16 KB), 4-wave blocks.
// Slot s (0..1023): row = s>>3, phys chunk = s&7, data chunk c = (s&7)^(row&7).
// LDS dest = wave-uniform base + lane*16 (m104-safe).
// ---------------------------------------------------------------------------
__device__ __forceinline__ void stage64(ushort* lds, const __bf16* gbase,
                                        int ldg, int wave, int lane) {
#pragma unroll
    for (int t = 0; t < 4; ++t) {
        const int slot = wave * 256 + t * 64 + lane;
        const int row  = slot >> 3;
        const int c    = (slot & 7) ^ (row & 7);
        __builtin_amdgcn_global_load_lds(
            (const __attribute__((address_space(1))) void*)(gbase + (size_t)row * ldg + c * 8),
            (__attribute__((address_space(3))) void*)(lds + (size_t)slot * 8),
            16, 0, 0);
    }
}

// ---------------------------------------------------------------------------
// prep_x: one pass over x. Writes xb = bf16(x) [B,S,E] and xT = bf16(x^T) [B,E,S]
// ---------------------------------------------------------------------------
__global__ void prep_x(const float* __restrict__ in, __bf16* __restrict__ xb,
                       __bf16* __restrict__ xT) {
    __shared__ float tile[32][33];
    const int b  = blockIdx.z;
    const int e0 = blockIdx.x * 32;
    const int s0 = blockIdx.y * 32;
    const float* ip = in + (size_t)b * Ss * Ee;
    __bf16* xbp = xb + (size_t)b * Ss * Ee;
    __bf16* xTp = xT + (size_t)b * Ee * Ss;
    for (int i = threadIdx.y; i < 32; i += 8) {
        const float v = ip[(size_t)(s0 + i) * Ee + e0 + threadIdx.x];
        tile[i][threadIdx.x] = v;
        xbp[(size_t)(s0 + i) * Ee + e0 + threadIdx.x] = (__bf16)v;
    }
    __syncthreads();
    for (int i = threadIdx.y; i < 32; i += 8)
        xTp[(size_t)(e0 + i) * Ss + s0 + threadIdx.x] = (__bf16)tile[threadIdx.x][i];
}

// ---------------------------------------------------------------------------
// Transpose 512x512: f32 in -> bf16 out. blockIdx.z selects Wq/Wk.
// ---------------------------------------------------------------------------
__global__ void transpose_w(const float* __restrict__ Wq, const float* __restrict__ Wk,
                            __bf16* __restrict__ WqT, __bf16* __restrict__ WkT) {
    __shared__ float tile[32][33];
    const float* in = blockIdx.z ? Wk : Wq;
    __bf16* out = blockIdx.z ? WkT : WqT;
    const int x0 = blockIdx.x * 32;
    const int y0 = blockIdx.y * 32;
    for (int i = threadIdx.y; i < 32; i += 8)
        tile[i][threadIdx.x] = in[(size_t)(y0 + i) * 512 + (x0 + threadIdx.x)];
    __syncthreads();
    for (int i = threadIdx.y; i < 32; i += 8)
        out[(size_t)(x0 + i) * 512 + (y0 + threadIdx.x)] = (__bf16)tile[threadIdx.x][i];
}

// ---------------------------------------------------------------------------
// Projection GEMM (NT): Out = relu(X @ W + b), 128x128 tile, BK=64 (8 steps),
// async+swizzle staging, LDS-transposed vector epilogue store.
// ---------------------------------------------------------------------------
__global__ __launch_bounds__(256, 4) void proj_kernel(
    const __bf16* __restrict__ X,
    const __bf16* __restrict__ WqT, const __bf16* __restrict__ WkT,
    const float* __restrict__ bq, const float* __restrict__ bk,
    __bf16* __restrict__ qb, __bf16* __restrict__ kb)
{
    __shared__ __align__(16) ushort smem[2 * 128 * 64];   // As | Bs, 32 KB
    ushort* As = smem;
    ushort* Bs = smem + 128 * 64;
    const __bf16* WT  = blockIdx.z ? WkT : WqT;
    const float* bias = blockIdx.z ? bk : bq;
    __bf16* Out       = blockIdx.z ? kb : qb;

    const int tid = threadIdx.x;
    const int wave = tid >> 6, lane = tid & 63, quad = lane >> 4, l16 = lane & 15;
    const int wm = (wave >> 1) * 64, wn = (wave & 1) * 64;
    const int m0 = blockIdx.y * 128, n0 = blockIdx.x * 128;
    const int K = 512;
    const int sw0 = ((quad)     ^ (l16 & 7)) * 8;   // k-half 0 chunk offset
    const int sw1 = ((quad + 4) ^ (l16 & 7)) * 8;   // k-half 1

    f32x4 acc[4][4];
    f32x4 zero = {0.f, 0.f, 0.f, 0.f};
    for (int i = 0; i < 4; i++) for (int j = 0; j < 4; j++) acc[i][j] = zero;

    for (int k0 = 0; k0 < K; k0 += 64) {
        stage64(As, X  + (size_t)m0 * K + k0, K, wave, lane);
        stage64(Bs, WT + (size_t)n0 * K + k0, K, wave, lane);
        __syncthreads();
        #pragma unroll
        for (int h = 0; h < 2; h++) {
            const int sw = h ? sw1 : sw0;
            bf16x8 af[4], bfr[4];
            for (int i = 0; i < 4; i++) af[i]  = *(bf16x8*)&As[(wm + i * 16 + l16) * 64 + sw];
            for (int j = 0; j < 4; j++) bfr[j] = *(bf16x8*)&Bs[(wn + j * 16 + l16) * 64 + sw];
            for (int i = 0; i < 4; i++)
                for (int j = 0; j < 4; j++)
                    acc[i][j] = __builtin_amdgcn_mfma_f32_16x16x32_bf16(af[i], bfr[j], acc[i][j], 0, 0, 0);
        }
        __syncthreads();
    }

    // epilogue: bias+relu -> per-wave LDS patch -> coalesced bf16x8 stores
    ushort* patch = smem + wave * 4096;   // 64x64 bf16
    for (int j = 0; j < 4; j++) {
        const float bv = bias[n0 + wn + j * 16 + l16];
        for (int i = 0; i < 4; i++)
            for (int rr = 0; rr < 4; rr++) {
                float v = acc[i][j][rr] + bv;
                v = v > 0.f ? v : 0.f;
                patch[(i * 16 + quad * 4 + rr) * 64 + j * 16 + l16] = ((ushort2*)&v)[0].y;
            }
    }
    __syncthreads();
    #pragma unroll
    for (int it = 0; it < 8; it++) {
        const int lr = it * 8 + (lane >> 3);
        const int lc = (lane & 7) * 8;
        const bf16x8 v = *(const bf16x8*)&patch[lr * 64 + lc];
        *(bf16x8*)&Out[(size_t)(m0 + wm + lr) * 512 + n0 + wn + lc] = v;
    }
}

// ---------------------------------------------------------------------------
// Scores GEMM (NT), BK=64 (8 steps), + fused column-softmax tile stats +
// bf16 P output via LDS-transposed coalesced stores.
// 1-D grid, XCD=batch swizzle: b = id&7 keeps qb/kb batch strips L2-resident.
// ---------------------------------------------------------------------------
__global__ __launch_bounds__(256, 4) void scores_kernel(
    const __bf16* __restrict__ Q,   // [B*S, D] bf16
    const __bf16* __restrict__ Km,  // [B*S, D] bf16
    __bf16* __restrict__ P,         // [B, S, S] bf16
    float* __restrict__ Mp,         // [QSPLIT, B, S]
    float* __restrict__ Lp)         // [QSPLIT, B, S]
{
    __shared__ __align__(16) ushort smem[2 * 128 * 64];   // As | Bs, 32 KB
    __shared__ float stats[512];                          // Ms | Ls
    ushort* As = smem;
    ushort* Bs = smem + 128 * 64;
    const int id = blockIdx.x;            // 0..2047
    const int b = id & 7;
    const int rest = id >> 3;             // 0..255
    const int qy = rest >> 4;             // q tile 0..15
    const int m0 = qy * 128;
    const int n0 = (rest & 15) * 128;     // k tile
    const __bf16* A  = Q  + (size_t)b * Ss * Dd;
    const __bf16* Bp = Km + (size_t)b * Ss * Dd;
    __bf16* C = P + (size_t)b * Ss * Ss;

    const int tid = threadIdx.x;
    const int wave = tid >> 6, lane = tid & 63, quad = lane >> 4, l16 = lane & 15;
    const int wm = (wave >> 1) * 64, wn = (wave & 1) * 64;
    const int sw0 = ((quad)     ^ (l16 & 7)) * 8;
    const int sw1 = ((quad + 4) ^ (l16 & 7)) * 8;
    const float scale = 0.044194173824159216f; // 1/sqrt(512)

    f32x4 acc[4][4];
    f32x4 zero = {0.f, 0.f, 0.f, 0.f};
    for (int i = 0; i < 4; i++) for (int j = 0; j < 4; j++) acc[i][j] = zero;

    for (int k0 = 0; k0 < Dd; k0 += 64) {
        stage64(As, A  + (size_t)m0 * Dd + k0, Dd, wave, lane);
        stage64(Bs, Bp + (size_t)n0 * Dd + k0, Dd, wave, lane);
        __syncthreads();
        #pragma unroll
        for (int h = 0; h < 2; h++) {
            const int sw = h ? sw1 : sw0;
            bf16x8 af[4], bfr[4];
            for (int i = 0; i < 4; i++) af[i]  = *(bf16x8*)&As[(wm + i * 16 + l16) * 64 + sw];
            for (int j = 0; j < 4; j++) bfr[j] = *(bf16x8*)&Bs[(wn + j * 16 + l16) * 64 + sw];
            for (int i = 0; i < 4; i++)
                for (int j = 0; j < 4; j++)
                    acc[i][j] = __builtin_amdgcn_mfma_f32_16x16x32_bf16(af[i], bfr[j], acc[i][j], 0, 0, 0);
        }
        __syncthreads();
    }

    // ---- tile column max (unscaled; scale>0 commutes with max) ----
    float* Ms = stats;          // 256 f32
    float* Ls = stats + 256;    // 256 f32
    const int half = wave >> 1;
    float mj[4];
    for (int j = 0; j < 4; j++) {
        float m = -1e30f;
        for (int i = 0; i < 4; i++)
            for (int rr = 0; rr < 4; rr++)
                m = fmaxf(m, acc[i][j][rr]);
        m = fmaxf(m, __shfl_xor(m, 16));
        m = fmaxf(m, __shfl_xor(m, 32));
        mj[j] = m;
    }
    if (quad == 0)
        for (int j = 0; j < 4; j++) Ms[half * 128 + wn + j * 16 + l16] = mj[j];
    __syncthreads();
    float mt[4];
    for (int j = 0; j < 4; j++) {
        const int c = wn + j * 16 + l16;
        mt[j] = fmaxf(Ms[c], Ms[128 + c]);
    }
    // ---- exp -> per-wave LDS patch (reuses As/Bs) + column sums ----
    ushort* patch = smem + wave * 4096;   // 64x64 bf16
    float lj[4];
    for (int j = 0; j < 4; j++) {
        float l = 0.f;
        for (int i = 0; i < 4; i++)
            for (int rr = 0; rr < 4; rr++) {
                const float e = __expf((acc[i][j][rr] - mt[j]) * scale);
                patch[(i * 16 + quad * 4 + rr) * 64 + j * 16 + l16] = ((ushort2*)&e)[0].y;
                l += e;
            }
        l += __shfl_xor(l, 16);
        l += __shfl_xor(l, 32);
        lj[j] = l;
    }
    if (quad == 0)
        for (int j = 0; j < 4; j++) Ls[half * 128 + wn + j * 16 + l16] = lj[j];
    __syncthreads();
    if (tid < 128) {
        const size_t o = ((size_t)qy * Bb + b) * Ss + n0 + tid;
        Mp[o] = fmaxf(Ms[tid], Ms[128 + tid]) * scale;
        Lp[o] = Ls[tid] + Ls[128 + tid];
    }
    // ---- coalesced P store: 8 bf16x8 per thread ----
    #pragma unroll
    for (int it = 0; it < 8; it++) {
        const int lr = it * 8 + (lane >> 3);
        const int lc = (lane & 7) * 8;
        const bf16x8 v = *(const bf16x8*)&patch[lr * 64 + lc];
        *(bf16x8*)&C[(size_t)(m0 + wm + lr) * Ss + n0 + wn + lc] = v;
    }
}

// ---------------------------------------------------------------------------
// Combine QSPLIT tile partials -> per-tile correction table
// Corr[qy][b][k] = exp(Mp[qy][b][k] - m_global) / sumexp_global
// ---------------------------------------------------------------------------
__global__ void stats_combine(const float* __restrict__ Mp, const float* __restrict__ Lp,
                              float* __restrict__ Corr) {
    const int idx = blockIdx.x * 256 + threadIdx.x;  // over B*S columns
    float m = -1e30f;
    for (int qy = 0; qy < QSPLIT; qy++) m = fmaxf(m, Mp[(size_t)qy * Bb * Ss + idx]);
    float l = 0.f;
    for (int qy = 0; qy < QSPLIT; qy++)
        l += Lp[(size_t)qy * Bb * Ss + idx] * __expf(Mp[(size_t)qy * Bb * Ss + idx] - m);
    const float li = 1.0f / l;
    for (int qy = 0; qy < QSPLIT; qy++)
        Corr[(size_t)qy * Bb * Ss + idx] = __expf(Mp[(size_t)qy * Bb * Ss + idx] - m) * li;
}

// ---------------------------------------------------------------------------
// PV GEMM (NT) — unchanged from R8 (control). 64x128 block tile, 2 waves,
// wave tile 64x64, 1024 blocks, Corr global, XCD=batch swizzle, residual fused.
// ---------------------------------------------------------------------------
__global__ __launch_bounds__(128, 2) void pv_kernel(
    const __bf16* __restrict__ P,    // [B,S,S] bf16 tile-shifted exp scores
    const float* __restrict__ Corr,  // [QSPLIT,B,S]
    const __bf16* __restrict__ XT,   // [B,E,S] bf16
    const __bf16* __restrict__ XB,   // [B,S,E] bf16 (residual)
    float* __restrict__ Out)         // [B,S,E] f32
{
    __shared__ __align__(16) ushort As[64 * 32];    // 4 KB
    __shared__ __align__(16) ushort Bs[128 * 32];   // 8 KB
    const int id = blockIdx.x;            // 0..1023
    const int b = id & 7;
    const int rest = id >> 3;             // 0..127
    const int m0 = (rest >> 2) * 64;      // m tile 0..31 (64 rows)
    const int n0 = (rest & 3) * 128;      // e tile
    const int qy = m0 >> 7;               // 128-row scores-tile index
    const __bf16* A  = P  + (size_t)b * Ss * Ss;
    const __bf16* Bp = XT + (size_t)b * Ee * Ss;
    const float* Cr  = Corr + ((size_t)qy * Bb + b) * Ss;

    const int tid = threadIdx.x;
    const int wave = tid >> 6, lane = tid & 63, quad = lane >> 4, l16 = lane & 15;
    const int wn = wave * 64;
    const int sw = (quad ^ ((l16 >> 1) & 3)) * 8;
    const int r = tid >> 2, seg = (tid & 3) * 8;
    const int p8 = (((tid & 3) ^ ((r >> 1) & 3)) * 8);

    f32x4 acc[4][4];
    f32x4 zero = {0.f, 0.f, 0.f, 0.f};
    for (int i = 0; i < 4; i++) for (int j = 0; j < 4; j++) acc[i][j] = zero;

    const __bf16* Arow0 = A + (size_t)(m0 + r) * Ss;
    const __bf16* Arow1 = A + (size_t)(m0 + r + 32) * Ss;
    bf16x8 pr0 = *(const bf16x8*)&Arow0[seg];
    bf16x8 pr1 = *(const bf16x8*)&Arow1[seg];
    float4 cra = *(const float4*)&Cr[seg];
    float4 crb = *(const float4*)&Cr[seg + 4];

    for (int k0 = 0; k0 < Ss; k0 += 32) {
        stage_async2(Bs, Bp + (size_t)n0 * Ss + k0, Ss, wave, lane);
        float cv[8];
        cv[0] = cra.x; cv[1] = cra.y; cv[2] = cra.z; cv[3] = cra.w;
        cv[4] = crb.x; cv[5] = crb.y; cv[6] = crb.z; cv[7] = crb.w;
        bf16x8 o0, o1;
        #pragma unroll
        for (int t = 0; t < 8; t++) o0[t] = (__bf16)((float)pr0[t] * cv[t]);
        #pragma unroll
        for (int t = 0; t < 8; t++) o1[t] = (__bf16)((float)pr1[t] * cv[t]);
        *(bf16x8*)&As[r * 32 + p8]        = o0;
        *(bf16x8*)&As[(r + 32) * 32 + p8] = o1;
        __syncthreads();
        bf16x8 af[4], bfr[4];
        for (int i = 0; i < 4; i++) af[i]  = *(bf16x8*)&As[(i * 16 + l16) * 32 + sw];
        for (int j = 0; j < 4; j++) bfr[j] = *(bf16x8*)&Bs[(wn + j * 16 + l16) * 32 + sw];
        const int kn = (k0 + 32) & (Ss - 1);
        pr0 = *(const bf16x8*)&Arow0[kn + seg];
        pr1 = *(const bf16x8*)&Arow1[kn + seg];
        cra = *(const float4*)&Cr[kn + seg];
        crb = *(const float4*)&Cr[kn + seg + 4];
        for (int i = 0; i < 4; i++)
            for (int j = 0; j < 4; j++)
                acc[i][j] = __builtin_amdgcn_mfma_f32_16x16x32_bf16(af[i], bfr[j], acc[i][j], 0, 0, 0);
        __syncthreads();
    }

    for (int i = 0; i < 4; i++) {
        const int row = m0 + i * 16 + quad * 4;
        for (int j = 0; j < 4; j++) {
            const int col = n0 + wn + j * 16 + l16;
            for (int rr = 0; rr < 4; rr++) {
                const size_t idx = ((size_t)b * Ss + row + rr) * Ee + col;
                Out[idx] = (float)XB[idx] + acc[i][j][rr];
            }
        }
    }
}

// ---------------------------------------------------------------------------
extern "C" void kernel_launch(void* const* d_in, const int* in_sizes, int n_in,
                              void* d_out, int out_size, void* d_ws, size_t ws_size,
                              hipStream_t stream) {
    const float* x  = (const float*)d_in[0];
    const float* Wq = (const float*)d_in[1];
    const float* bq = (const float*)d_in[2];
    const float* Wk = (const float*)d_in[3];
    const float* bk = (const float*)d_in[4];
    float* out = (float*)d_out;

    char* ws = (char*)d_ws;
    size_t off = 0;
    auto alloc = [&](size_t bytes) -> void* {
        void* p = ws + off;
        off += (bytes + 255) & ~(size_t)255;
        return p;
    };
    __bf16* P    = (__bf16*)alloc((size_t)Bb * Ss * Ss * 2);      // 64 MiB
    __bf16* xb   = (__bf16*)alloc((size_t)Bb * Ss * Ee * 2);
    __bf16* qb   = (__bf16*)alloc((size_t)Bb * Ss * Dd * 2);
    __bf16* kb   = (__bf16*)alloc((size_t)Bb * Ss * Dd * 2);
    __bf16* xT   = (__bf16*)alloc((size_t)Bb * Ee * Ss * 2);
    __bf16* WqT  = (__bf16*)alloc((size_t)512 * 512 * 2);
    __bf16* WkT  = (__bf16*)alloc((size_t)512 * 512 * 2);
    float*  Mp   = (float*)alloc((size_t)QSPLIT * Bb * Ss * 4);
    float*  Lp   = (float*)alloc((size_t)QSPLIT * Bb * Ss * 4);
    float*  Corr = (float*)alloc((size_t)QSPLIT * Bb * Ss * 4);   // 1 MiB
    if (off > ws_size) return;

    prep_x<<<dim3(16, 64, 8), dim3(32, 8), 0, stream>>>(x, xb, xT);
    transpose_w<<<dim3(16, 16, 2), dim3(32, 8), 0, stream>>>(Wq, Wk, WqT, WkT);

    // q = relu(x Wq + bq), k = relu(x Wk + bk)   (BK=64, vector epilogue)
    proj_kernel<<<dim3(4, 128, 2), 256, 0, stream>>>(xb, WqT, WkT, bq, bk, qb, kb);

    // P = exp(q k^T / sqrt(E) - m_tile) bf16 + tile stats  (BK=64, XCD swizzle)
    scores_kernel<<<dim3(2048), 256, 0, stream>>>(qb, kb, P, Mp, Lp);
    stats_combine<<<dim3(Bb * Ss / 256), 256, 0, stream>>>(Mp, Lp, Corr);

    // out = xb + attn @ x   (unchanged control)
    pv_kernel<<<dim3(1024), 128, 0, stream>>>(P, Corr, xT, xb, out);
}